// Round 1
// baseline (1087.177 us; speedup 1.0000x reference)
//
#include <hip/hip_runtime.h>
#include <math.h>

#define BB 256
#define CC 500
#define LL 200
#define DD 64
#define HH 128
#define NUM_ITEMS 100000
#define BETA 0.7f
#define EPSV 1e-8f

__device__ __forceinline__ float softplus_f(float x) {
    // stable softplus: max(x,0) + log1p(exp(-|x|))
    float ax = fabsf(x);
    return fmaxf(x, 0.0f) + log1pf(__expf(-ax));
}

// Evaluates one 64->128->128->1 MLP for this thread's item.
// z[DD] in registers (constant-indexed), h1 spilled to this thread's LDS column.
__device__ __forceinline__ float mlp_one(const float z[DD], float* __restrict__ h1s, int tid,
    const float* __restrict__ W1, const float* __restrict__ b1,
    const float* __restrict__ W2, const float* __restrict__ b2,
    const float* __restrict__ W3)
{
    // ---- layer 1: h1[j] = softplus(b1[j] + sum_d z[d]*W1[d*H + j]) ----
    #pragma unroll 1
    for (int jc = 0; jc < HH; jc += 8) {
        float acc[8];
        #pragma unroll
        for (int i = 0; i < 8; ++i) acc[i] = b1[jc + i];          // uniform -> s_load
        #pragma unroll
        for (int d = 0; d < DD; ++d) {
            #pragma unroll
            for (int i = 0; i < 8; ++i)
                acc[i] = fmaf(z[d], W1[d * HH + jc + i], acc[i]); // weight uniform -> SGPR operand
        }
        #pragma unroll
        for (int i = 0; i < 8; ++i)
            h1s[(jc + i) * 64 + tid] = softplus_f(acc[i]);
    }
    __syncthreads(); // single wave: effectively a waitcnt; cheap safety

    // ---- layer 2 + 3: out = sum_j softplus(b2[j] + sum_k h1[k]*W2[k*H+j]) * W3[j] ----
    float out = 0.0f;
    #pragma unroll 1
    for (int jc = 0; jc < HH; jc += 8) {
        float acc[8];
        #pragma unroll
        for (int i = 0; i < 8; ++i) acc[i] = b2[jc + i];
        #pragma unroll 4
        for (int k = 0; k < HH; ++k) {
            float hk = h1s[k * 64 + tid];
            #pragma unroll
            for (int i = 0; i < 8; ++i)
                acc[i] = fmaf(hk, W2[k * HH + jc + i], acc[i]);
        }
        #pragma unroll
        for (int i = 0; i < 8; ++i)
            out += softplus_f(acc[i]) * W3[jc + i];
    }
    return softplus_f(out) + EPSV;
}

// One thread per item; block = 64 threads (1 wave). 32 KB LDS for h1 spill.
__global__ __launch_bounds__(64) void mlp_kernel(
    const float* __restrict__ emb,
    const float* __restrict__ W1, const float* __restrict__ b1,
    const float* __restrict__ W2, const float* __restrict__ b2,
    const float* __restrict__ W3,
    const float* __restrict__ V1, const float* __restrict__ c1,
    const float* __restrict__ V2, const float* __restrict__ c2,
    const float* __restrict__ V3,
    float* __restrict__ mu, float* __restrict__ alpha)
{
    __shared__ float h1s[HH * 64];
    int tid = threadIdx.x;
    int item = blockIdx.x * 64 + tid;
    int src = (item < NUM_ITEMS) ? item : 0;

    float z[DD];
    #pragma unroll
    for (int d = 0; d < DD; ++d) z[d] = emb[(size_t)src * DD + d];

    float m = mlp_one(z, h1s, tid, W1, b1, W2, b2, W3);
    __syncthreads();
    float a = mlp_one(z, h1s, tid, V1, c1, V2, c2, V3);

    if (item < NUM_ITEMS) {
        mu[item] = m;
        alpha[item] = a;
    }
}

// One wave per (b,c) row: reduce exp(-BETA*(q-hist))*[hist<q] over L=200,
// then out = mu[item] + alpha[item] * h.
__global__ __launch_bounds__(256) void hawkes_kernel(
    const int* __restrict__ items,
    const float* __restrict__ qt,
    const float* __restrict__ hist,
    const float* __restrict__ mu,
    const float* __restrict__ alpha,
    float* __restrict__ out)
{
    int w = blockIdx.x * 4 + (threadIdx.x >> 6); // global row index (b*C + c)
    int lane = threadIdx.x & 63;
    int b = w / CC;
    float q = qt[b];
    const float* row = hist + (size_t)w * LL;

    float s = 0.0f;
    for (int i = lane; i < LL; i += 64) {
        float hv = row[i];
        float e = __expf(-BETA * (q - hv));
        s += (hv < q) ? e : 0.0f;
    }
    #pragma unroll
    for (int off = 32; off; off >>= 1) s += __shfl_down(s, off);

    if (lane == 0) {
        int it = items[w];
        out[w] = fmaf(alpha[it], s, mu[it]);
    }
}

extern "C" void kernel_launch(void* const* d_in, const int* in_sizes, int n_in,
                              void* d_out, int out_size, void* d_ws, size_t ws_size,
                              hipStream_t stream)
{
    const int*   items = (const int*)  d_in[0];
    const float* qt    = (const float*)d_in[1];
    const float* hist  = (const float*)d_in[2];
    const float* emb   = (const float*)d_in[3];
    const float* W1    = (const float*)d_in[4];
    const float* b1    = (const float*)d_in[5];
    const float* W2    = (const float*)d_in[6];
    const float* b2    = (const float*)d_in[7];
    const float* W3    = (const float*)d_in[8];
    const float* V1    = (const float*)d_in[9];
    const float* c1    = (const float*)d_in[10];
    const float* V2    = (const float*)d_in[11];
    const float* c2    = (const float*)d_in[12];
    const float* V3    = (const float*)d_in[13];

    float* out   = (float*)d_out;
    float* mu    = (float*)d_ws;            // NUM_ITEMS floats
    float* alpha = mu + NUM_ITEMS;          // NUM_ITEMS floats (800 KB total)

    int mlp_blocks = (NUM_ITEMS + 63) / 64; // 1563 blocks of 1 wave
    mlp_kernel<<<mlp_blocks, 64, 0, stream>>>(emb, W1, b1, W2, b2, W3,
                                              V1, c1, V2, c2, V3, mu, alpha);

    int rows = BB * CC;                     // 128000, 4 waves/block
    hawkes_kernel<<<rows / 4, 256, 0, stream>>>(items, qt, hist, mu, alpha, out);
}

// Round 2
// 447.671 us; speedup vs baseline: 2.4285x; 2.4285x over previous
//
#include <hip/hip_runtime.h>
#include <math.h>

#define BB 256
#define CC 500
#define LL 200
#define DD 64
#define HH 128
#define NUM_ITEMS 100000
#define BETA 0.7f
#define EPSV 1e-8f

typedef _Float16 half8 __attribute__((ext_vector_type(8)));
typedef float floatx4 __attribute__((ext_vector_type(4)));

__device__ __forceinline__ float softplus_f(float x) {
    // stable softplus: max(x,0) + log(1+exp(-|x|)); 1+t is well-conditioned (t in (0,1])
    float t = __expf(-fabsf(x));
    return fmaxf(x, 0.0f) + __logf(1.0f + t);
}

// ws f16 layout: W1t_base[128][64] @0, W2t_base[128][128] @8192,
//                W1t_exc @24576,     W2t_exc @32768        (49152 f16 total)
__global__ __launch_bounds__(256) void prep_w(
    const float* __restrict__ W1, const float* __restrict__ W2,
    const float* __restrict__ V1, const float* __restrict__ V2,
    _Float16* __restrict__ wb)
{
    int t = blockIdx.x * 256 + threadIdx.x;
    if (t >= 49152) return;
    float v;
    if (t < 8192)       { int n = t >> 6,  k = t & 63;             v = W1[k * HH + n]; }
    else if (t < 24576) { int u = t - 8192;  int n = u >> 7, k = u & 127; v = W2[k * HH + n]; }
    else if (t < 32768) { int u = t - 24576; int n = u >> 6, k = u & 63;  v = V1[k * HH + n]; }
    else                { int u = t - 32768; int n = u >> 7, k = u & 127; v = V2[k * HH + n]; }
    wb[t] = (_Float16)v;
}

// One 64->128->128->1 MLP for a 64-item tile held by one wave.
// zf: A-frags (f16) in registers. h1s: 64 x 136 f16 LDS (padded, b128-aligned).
__device__ __forceinline__ void mlp_eval(
    const half8 (&zf)[4][2], _Float16* __restrict__ h1s,
    const _Float16* __restrict__ W1t, const _Float16* __restrict__ W2t,
    const float* __restrict__ b1, const float* __restrict__ b2,
    const float* __restrict__ W3,
    float* __restrict__ outp, int ibase, int lane)
{
    int quad = lane >> 4, l15 = lane & 15;

    // ---- layer 1: two n-halves of 64 cols each (keeps acc at 64 VGPRs) ----
    #pragma unroll
    for (int h = 0; h < 2; ++h) {
        floatx4 acc[4][4];
        #pragma unroll
        for (int n = 0; n < 4; ++n) {
            float bv = b1[(h * 4 + n) * 16 + l15];
            #pragma unroll
            for (int mt = 0; mt < 4; ++mt) acc[mt][n] = (floatx4){bv, bv, bv, bv};
        }
        half8 wf[4][2];
        #pragma unroll
        for (int n = 0; n < 4; ++n)
            #pragma unroll
            for (int kt = 0; kt < 2; ++kt)
                wf[n][kt] = *(const half8*)(W1t + ((h * 4 + n) * 16 + l15) * DD + kt * 32 + quad * 8);
        #pragma unroll
        for (int kt = 0; kt < 2; ++kt)
            #pragma unroll
            for (int n = 0; n < 4; ++n)
                #pragma unroll
                for (int mt = 0; mt < 4; ++mt)
                    acc[mt][n] = __builtin_amdgcn_mfma_f32_16x16x32_f16(zf[mt][kt], wf[n][kt], acc[mt][n], 0, 0, 0);
        // softplus -> LDS in [item][j] layout (stride 136 f16 = 272 B, 16B-aligned rows)
        #pragma unroll
        for (int mt = 0; mt < 4; ++mt)
            #pragma unroll
            for (int n = 0; n < 4; ++n)
                #pragma unroll
                for (int r = 0; r < 4; ++r) {
                    int it = mt * 16 + quad * 4 + r;
                    int j  = (h * 4 + n) * 16 + l15;
                    h1s[it * 136 + j] = (_Float16)softplus_f(acc[mt][n][r]);
                }
    }
    __syncthreads();

    // ---- layer 2 + 3 ----
    float sacc[4][4];
    #pragma unroll
    for (int mt = 0; mt < 4; ++mt)
        #pragma unroll
        for (int r = 0; r < 4; ++r) sacc[mt][r] = 0.0f;

    #pragma unroll
    for (int h = 0; h < 2; ++h) {
        floatx4 acc[4][4];
        #pragma unroll
        for (int n = 0; n < 4; ++n) {
            float bv = b2[(h * 4 + n) * 16 + l15];
            #pragma unroll
            for (int mt = 0; mt < 4; ++mt) acc[mt][n] = (floatx4){bv, bv, bv, bv};
        }
        #pragma unroll
        for (int kt = 0; kt < 4; ++kt) {
            half8 af[4];
            #pragma unroll
            for (int mt = 0; mt < 4; ++mt)
                af[mt] = *(const half8*)(h1s + (mt * 16 + l15) * 136 + kt * 32 + quad * 8);
            half8 wf[4];
            #pragma unroll
            for (int n = 0; n < 4; ++n)
                wf[n] = *(const half8*)(W2t + ((h * 4 + n) * 16 + l15) * HH + kt * 32 + quad * 8);
            #pragma unroll
            for (int n = 0; n < 4; ++n)
                #pragma unroll
                for (int mt = 0; mt < 4; ++mt)
                    acc[mt][n] = __builtin_amdgcn_mfma_f32_16x16x32_f16(af[mt], wf[n], acc[mt][n], 0, 0, 0);
        }
        #pragma unroll
        for (int n = 0; n < 4; ++n) {
            float w3 = W3[(h * 4 + n) * 16 + l15];
            #pragma unroll
            for (int mt = 0; mt < 4; ++mt)
                #pragma unroll
                for (int r = 0; r < 4; ++r)
                    sacc[mt][r] += softplus_f(acc[mt][n][r]) * w3;
        }
    }
    // reduce over the 16 j-lanes (xor over low 4 bits), then write
    #pragma unroll
    for (int mt = 0; mt < 4; ++mt)
        #pragma unroll
        for (int r = 0; r < 4; ++r) {
            float s = sacc[mt][r];
            s += __shfl_xor(s, 1, 64);
            s += __shfl_xor(s, 2, 64);
            s += __shfl_xor(s, 4, 64);
            s += __shfl_xor(s, 8, 64);
            if (l15 == 0) {
                int item = ibase + mt * 16 + quad * 4 + r;
                if (item < NUM_ITEMS) outp[item] = softplus_f(s) + EPSV;
            }
        }
}

// One wave per block; 64 items per block; both MLPs share z-frags + h1 LDS.
__global__ __launch_bounds__(64) void mlp_mfma(
    const float* __restrict__ emb, const _Float16* __restrict__ wb,
    const float* __restrict__ b1, const float* __restrict__ b2, const float* __restrict__ W3,
    const float* __restrict__ c1, const float* __restrict__ c2, const float* __restrict__ V3,
    float* __restrict__ mu, float* __restrict__ alpha)
{
    __shared__ _Float16 h1s[64 * 136];
    int lane = threadIdx.x;
    int quad = lane >> 4, l15 = lane & 15;
    int ibase = blockIdx.x * 64;

    half8 zf[4][2];
    #pragma unroll
    for (int mt = 0; mt < 4; ++mt) {
        int item = ibase + mt * 16 + l15;
        int src = item < NUM_ITEMS ? item : NUM_ITEMS - 1;
        const float* p = emb + (size_t)src * DD + quad * 8;
        #pragma unroll
        for (int kt = 0; kt < 2; ++kt) {
            floatx4 v0 = *(const floatx4*)(p + kt * 32);
            floatx4 v1 = *(const floatx4*)(p + kt * 32 + 4);
            half8 z;
            #pragma unroll
            for (int j = 0; j < 4; ++j) { z[j] = (_Float16)v0[j]; z[4 + j] = (_Float16)v1[j]; }
            zf[mt][kt] = z;
        }
    }
    mlp_eval(zf, h1s, wb, wb + 8192, b1, b2, W3, mu, ibase, lane);
    __syncthreads();
    mlp_eval(zf, h1s, wb + 24576, wb + 32768, c1, c2, V3, alpha, ibase, lane);
}

// Thread-per-row Hawkes: 50 float4 loads, 4 independent accumulators, no shuffles.
__global__ __launch_bounds__(256) void hawkes_kernel(
    const int* __restrict__ items,
    const float* __restrict__ qt,
    const float* __restrict__ hist,
    const float* __restrict__ mu,
    const float* __restrict__ alpha,
    float* __restrict__ out)
{
    int row = blockIdx.x * 256 + threadIdx.x;   // 0 .. 127999 exactly
    int b = row / CC;
    float q = qt[b];
    const float4* r4 = (const float4*)(hist + (size_t)row * LL);
    float s0 = 0.f, s1 = 0.f, s2 = 0.f, s3 = 0.f;
    #pragma unroll 5
    for (int i = 0; i < LL / 4; ++i) {
        float4 v = r4[i];
        s0 += (v.x < q) ? __expf(-BETA * (q - v.x)) : 0.f;
        s1 += (v.y < q) ? __expf(-BETA * (q - v.y)) : 0.f;
        s2 += (v.z < q) ? __expf(-BETA * (q - v.z)) : 0.f;
        s3 += (v.w < q) ? __expf(-BETA * (q - v.w)) : 0.f;
    }
    float s = (s0 + s1) + (s2 + s3);
    int it = items[row];
    out[row] = fmaf(alpha[it], s, mu[it]);
}

extern "C" void kernel_launch(void* const* d_in, const int* in_sizes, int n_in,
                              void* d_out, int out_size, void* d_ws, size_t ws_size,
                              hipStream_t stream)
{
    const int*   items = (const int*)  d_in[0];
    const float* qt    = (const float*)d_in[1];
    const float* hist  = (const float*)d_in[2];
    const float* emb   = (const float*)d_in[3];
    const float* W1    = (const float*)d_in[4];
    const float* b1    = (const float*)d_in[5];
    const float* W2    = (const float*)d_in[6];
    const float* b2    = (const float*)d_in[7];
    const float* W3    = (const float*)d_in[8];
    const float* V1    = (const float*)d_in[9];
    const float* c1    = (const float*)d_in[10];
    const float* V2    = (const float*)d_in[11];
    const float* c2    = (const float*)d_in[12];
    const float* V3    = (const float*)d_in[13];

    float* out = (float*)d_out;
    _Float16* wb = (_Float16*)d_ws;                       // 98304 B of f16 weights
    float* mu    = (float*)((char*)d_ws + 98304);         // 100000 floats
    float* alpha = mu + NUM_ITEMS;                        // 100000 floats

    prep_w<<<192, 256, 0, stream>>>(W1, W2, V1, V2, wb);

    int mlp_blocks = (NUM_ITEMS + 63) / 64;               // 1563
    mlp_mfma<<<mlp_blocks, 64, 0, stream>>>(emb, wb, b1, b2, W3, c1, c2, V3, mu, alpha);

    hawkes_kernel<<<(BB * CC) / 256, 256, 0, stream>>>(items, qt, hist, mu, alpha, out);
}

// Round 3
// 260.767 us; speedup vs baseline: 4.1691x; 1.7167x over previous
//
#include <hip/hip_runtime.h>
#include <math.h>

#define BB 256
#define CC 500
#define LL 200
#define DD 64
#define HH 128
#define NUM_ITEMS 100000
#define BETA 0.7f
#define EPSV 1e-8f

#define TM 32                 // items per wave
#define WPB 4                 // waves per block
#define IPB (TM * WPB)        // 128 items per block
#define NBLK ((NUM_ITEMS + IPB - 1) / IPB)   // 782 blocks per MLP

typedef _Float16 half8 __attribute__((ext_vector_type(8)));
typedef float floatx4 __attribute__((ext_vector_type(4)));

__device__ __forceinline__ float softplus_f(float x) {
    // stable softplus: max(x,0) + log(1+exp(-|x|))
    float t = __expf(-fabsf(x));
    return fmaxf(x, 0.0f) + __logf(1.0f + t);
}

// ws f16 layout: W1t_base[128][64] @0, W2t_base[128][128] @8192,
//                W1t_exc @24576,     W2t_exc @32768        (49152 f16 total)
__global__ __launch_bounds__(256) void prep_w(
    const float* __restrict__ W1, const float* __restrict__ W2,
    const float* __restrict__ V1, const float* __restrict__ V2,
    _Float16* __restrict__ wb)
{
    int t = blockIdx.x * 256 + threadIdx.x;
    if (t >= 49152) return;
    float v;
    if (t < 8192)       { int n = t >> 6,  k = t & 63;             v = W1[k * HH + n]; }
    else if (t < 24576) { int u = t - 8192;  int n = u >> 7, k = u & 127; v = W2[k * HH + n]; }
    else if (t < 32768) { int u = t - 24576; int n = u >> 6, k = u & 63;  v = V1[k * HH + n]; }
    else                { int u = t - 32768; int n = u >> 7, k = u & 127; v = V2[k * HH + n]; }
    wb[t] = (_Float16)v;
}

// 4 waves/block, each wave: one 32-item tile through ONE 64->128->128->1 MLP.
// Blocks [0,NBLK) compute mu (base weights); [NBLK,2*NBLK) compute alpha (exc).
__global__ __launch_bounds__(256) void mlp_mfma(
    const float* __restrict__ emb, const _Float16* __restrict__ wb,
    const float* __restrict__ b1, const float* __restrict__ b2, const float* __restrict__ W3,
    const float* __restrict__ c1, const float* __restrict__ c2, const float* __restrict__ V3,
    float* __restrict__ mu, float* __restrict__ alpha)
{
    __shared__ _Float16 h1s[WPB][TM * 136];   // 34816 B: stride 136 f16, rows 16B-aligned
    int tid  = threadIdx.x;
    int wave = tid >> 6, lane = tid & 63;
    int quad = lane >> 4, l15 = lane & 15;

    int is_exc = blockIdx.x >= NBLK;                       // block-uniform
    int blk    = blockIdx.x - (is_exc ? NBLK : 0);
    int ibase  = blk * IPB + wave * TM;

    const _Float16* W1t = wb + (is_exc ? 24576 : 0);
    const _Float16* W2t = wb + (is_exc ? 32768 : 8192);
    const float* B1 = is_exc ? c1 : b1;
    const float* B2 = is_exc ? c2 : b2;
    const float* W3p = is_exc ? V3 : W3;
    float* outp = is_exc ? alpha : mu;
    _Float16* hs = &h1s[wave][0];

    // ---- A-frags: z for this wave's 32 items ----
    half8 zf[2][2];
    #pragma unroll
    for (int mt = 0; mt < 2; ++mt) {
        int item = ibase + mt * 16 + l15;
        int src = item < NUM_ITEMS ? item : NUM_ITEMS - 1;
        const float* p = emb + (size_t)src * DD + quad * 8;
        #pragma unroll
        for (int kt = 0; kt < 2; ++kt) {
            floatx4 v0 = *(const floatx4*)(p + kt * 32);
            floatx4 v1 = *(const floatx4*)(p + kt * 32 + 4);
            half8 z;
            #pragma unroll
            for (int j = 0; j < 4; ++j) { z[j] = (_Float16)v0[j]; z[4 + j] = (_Float16)v1[j]; }
            zf[mt][kt] = z;
        }
    }

    // ---- layer 1: [32 x 64] @ [64 x 128], two 64-col halves ----
    #pragma unroll
    for (int h = 0; h < 2; ++h) {
        floatx4 acc[2][4];
        #pragma unroll
        for (int n = 0; n < 4; ++n) {
            float bv = B1[(h * 4 + n) * 16 + l15];
            #pragma unroll
            for (int mt = 0; mt < 2; ++mt) acc[mt][n] = (floatx4){bv, bv, bv, bv};
        }
        half8 wf[4][2];
        #pragma unroll
        for (int n = 0; n < 4; ++n)
            #pragma unroll
            for (int kt = 0; kt < 2; ++kt)
                wf[n][kt] = *(const half8*)(W1t + ((h * 4 + n) * 16 + l15) * DD + kt * 32 + quad * 8);
        #pragma unroll
        for (int kt = 0; kt < 2; ++kt)
            #pragma unroll
            for (int n = 0; n < 4; ++n)
                #pragma unroll
                for (int mt = 0; mt < 2; ++mt)
                    acc[mt][n] = __builtin_amdgcn_mfma_f32_16x16x32_f16(zf[mt][kt], wf[n][kt], acc[mt][n], 0, 0, 0);
        #pragma unroll
        for (int mt = 0; mt < 2; ++mt)
            #pragma unroll
            for (int n = 0; n < 4; ++n)
                #pragma unroll
                for (int r = 0; r < 4; ++r) {
                    int it = mt * 16 + quad * 4 + r;
                    int j  = (h * 4 + n) * 16 + l15;
                    hs[it * 136 + j] = (_Float16)softplus_f(acc[mt][n][r]);
                }
    }
    __syncthreads();

    // ---- layer 2 + 3 ----
    float sacc[2][4];
    #pragma unroll
    for (int mt = 0; mt < 2; ++mt)
        #pragma unroll
        for (int r = 0; r < 4; ++r) sacc[mt][r] = 0.0f;

    #pragma unroll
    for (int h = 0; h < 2; ++h) {
        floatx4 acc[2][4];
        #pragma unroll
        for (int n = 0; n < 4; ++n) {
            float bv = B2[(h * 4 + n) * 16 + l15];
            #pragma unroll
            for (int mt = 0; mt < 2; ++mt) acc[mt][n] = (floatx4){bv, bv, bv, bv};
        }
        #pragma unroll
        for (int kt = 0; kt < 4; ++kt) {
            half8 af[2];
            #pragma unroll
            for (int mt = 0; mt < 2; ++mt)
                af[mt] = *(const half8*)(hs + (mt * 16 + l15) * 136 + kt * 32 + quad * 8);
            half8 wf[4];
            #pragma unroll
            for (int n = 0; n < 4; ++n)
                wf[n] = *(const half8*)(W2t + ((h * 4 + n) * 16 + l15) * HH + kt * 32 + quad * 8);
            #pragma unroll
            for (int n = 0; n < 4; ++n)
                #pragma unroll
                for (int mt = 0; mt < 2; ++mt)
                    acc[mt][n] = __builtin_amdgcn_mfma_f32_16x16x32_f16(af[mt], wf[n], acc[mt][n], 0, 0, 0);
        }
        #pragma unroll
        for (int n = 0; n < 4; ++n) {
            float w3 = W3p[(h * 4 + n) * 16 + l15];
            #pragma unroll
            for (int mt = 0; mt < 2; ++mt)
                #pragma unroll
                for (int r = 0; r < 4; ++r)
                    sacc[mt][r] += softplus_f(acc[mt][n][r]) * w3;
        }
    }
    // reduce over the 16 j-lanes, write 32 outputs
    #pragma unroll
    for (int mt = 0; mt < 2; ++mt)
        #pragma unroll
        for (int r = 0; r < 4; ++r) {
            float s = sacc[mt][r];
            s += __shfl_xor(s, 1, 64);
            s += __shfl_xor(s, 2, 64);
            s += __shfl_xor(s, 4, 64);
            s += __shfl_xor(s, 8, 64);
            if (l15 == 0) {
                int item = ibase + mt * 16 + quad * 4 + r;
                if (item < NUM_ITEMS) outp[item] = softplus_f(s) + EPSV;
            }
        }
}

// Wave-per-row: lanes 0-49 each load one float4 (800B coalesced), xor-reduce,
// out = mu[it] + alpha[it]*exp(-beta*q)*sum(exp(beta*h)*[h<q]).
__global__ __launch_bounds__(256) void hawkes_kernel(
    const int* __restrict__ items,
    const float* __restrict__ qt,
    const float* __restrict__ hist,
    const float* __restrict__ mu,
    const float* __restrict__ alpha,
    float* __restrict__ out)
{
    int w = blockIdx.x * 4 + (threadIdx.x >> 6);  // row = b*C + c
    int lane = threadIdx.x & 63;
    float q = qt[w / CC];

    float s = 0.0f;
    if (lane < LL / 4) {
        float4 v = *(const float4*)(hist + (size_t)w * LL + lane * 4);
        s  = (v.x < q) ? __expf(BETA * v.x) : 0.f;
        s += (v.y < q) ? __expf(BETA * v.y) : 0.f;
        s += (v.z < q) ? __expf(BETA * v.z) : 0.f;
        s += (v.w < q) ? __expf(BETA * v.w) : 0.f;
    }
    #pragma unroll
    for (int off = 1; off < 64; off <<= 1) s += __shfl_xor(s, off, 64);

    if (lane == 0) {
        int it = items[w];
        out[w] = fmaf(alpha[it] * __expf(-BETA * q), s, mu[it]);
    }
}

extern "C" void kernel_launch(void* const* d_in, const int* in_sizes, int n_in,
                              void* d_out, int out_size, void* d_ws, size_t ws_size,
                              hipStream_t stream)
{
    const int*   items = (const int*)  d_in[0];
    const float* qt    = (const float*)d_in[1];
    const float* hist  = (const float*)d_in[2];
    const float* emb   = (const float*)d_in[3];
    const float* W1    = (const float*)d_in[4];
    const float* b1    = (const float*)d_in[5];
    const float* W2    = (const float*)d_in[6];
    const float* b2    = (const float*)d_in[7];
    const float* W3    = (const float*)d_in[8];
    const float* V1    = (const float*)d_in[9];
    const float* c1    = (const float*)d_in[10];
    const float* V2    = (const float*)d_in[11];
    const float* c2    = (const float*)d_in[12];
    const float* V3    = (const float*)d_in[13];

    float* out = (float*)d_out;
    _Float16* wb = (_Float16*)d_ws;                       // 98304 B of f16 weights
    float* mu    = (float*)((char*)d_ws + 98304);         // 100000 floats
    float* alpha = mu + NUM_ITEMS;                        // 100000 floats

    prep_w<<<192, 256, 0, stream>>>(W1, W2, V1, V2, wb);

    mlp_mfma<<<2 * NBLK, 256, 0, stream>>>(emb, wb, b1, b2, W3, c1, c2, V3, mu, alpha);

    hawkes_kernel<<<(BB * CC) / 4, 256, 0, stream>>>(items, qt, hist, mu, alpha, out);
}